// Round 11
// baseline (145.572 us; speedup 1.0000x reference)
//
#include <hip/hip_runtime.h>

// Histogram2D: x (16, 131072, 2) f32 in [0,1) -> counts (16, 100, 100) f32, normalized.
// Round 11 probe: is the LDS-atomic serializer (3.3 cyc per fired lane, confirmed
// r3/r5/r9/r10) one pipe per CU or per address-region? Split each block's histogram
// into TWO 40KB sub-histograms: waves 0-7 -> copy A, waves 8-15 -> copy B
// (80KB/block, still 2 blocks/CU = 160KB, occupancy unchanged). Fired-lane count
// identical; if the engine parallelizes across regions -> hist ~55-65us, else ~90.
// Flush sums A+B bin-pairs -> coalesced u64 atomics into 640KB per-batch accum (r9).

#define BINS     100
#define NBINS2   (BINS * BINS)     // 10000
#define NPAIR    (NBINS2 / 2)      // 5000 u64 bin-pairs
#define NPOINTS  131072
#define NBATCH   16
#define PPB      32                // partial blocks per batch
#define CHUNK    (NPOINTS / PPB)   // 4096 points per block
#define THREADS  1024
#define NPART    (NBATCH * PPB)    // 512
#define QSCALE   33554432.0f       // 2^25 fixed-point scale
#define QINV     (1.0 / 33554432.0)

__device__ __forceinline__ void accum_point_q(unsigned* lh, float x0, float x1) {
    // anchor bin: floor(x*100) clipped (verified numerics, r4-r10)
    int i0 = __float2int_rd(__fmul_rn(x0, 100.0f)); i0 = min(max(i0, 0), BINS - 1);
    int i1 = __float2int_rd(__fmul_rn(x1, 100.0f)); i1 = min(max(i1, 0), BINS - 1);
    const float fi0 = (float)i0, fi1 = (float)i1;
    const float c00 = __fmul_rn(0.01f, fi0 + 0.5f);
    const float c10 = __fmul_rn(0.01f, fi1 + 0.5f);
    const float e00 = fabsf(__fsub_rn(x0, c00));
    const float e10 = fabsf(__fsub_rn(x1, c10));
    float e0m = fabsf(__fsub_rn(x0, __fmul_rn(0.01f, fi0 - 0.5f)));
    float e0p = fabsf(__fsub_rn(x0, __fmul_rn(0.01f, fi0 + 1.5f)));
    float e1m = fabsf(__fsub_rn(x1, __fmul_rn(0.01f, fi1 - 0.5f)));
    float e1p = fabsf(__fsub_rn(x1, __fmul_rn(0.01f, fi1 + 1.5f)));
    e0m = (i0 > 0)        ? e0m : 1e9f;   // OOB -> w < 0 -> masked off
    e0p = (i0 < BINS - 1) ? e0p : 1e9f;
    e1m = (i1 > 0)        ? e1m : 1e9f;
    e1p = (i1 < BINS - 1) ? e1p : 1e9f;
    // only the leaned-toward +/-2 offset can fire, paired with the other coord's own bin
    const bool up0 = (x0 > c00), up1 = (x1 > c10);
    const int   f0  = up0 ? i0 + 2 : i0 - 2;
    const int   f1  = up1 ? i1 + 2 : i1 - 2;
    const float ff0 = up0 ? fi0 + 2.0f : fi0 - 2.0f;
    const float ff1 = up1 ? fi1 + 2.0f : fi1 - 2.0f;
    float e0f = fabsf(__fsub_rn(x0, __fmul_rn(0.01f, ff0 + 0.5f)));
    float e1f = fabsf(__fsub_rn(x1, __fmul_rn(0.01f, ff1 + 0.5f)));
    e0f = ((unsigned)f0 < (unsigned)BINS) ? e0f : 1e9f;
    e1f = ((unsigned)f1 < (unsigned)BINS) ? e1f : 1e9f;

    const int rm = max(i0 - 1, 0) * BINS;
    const int r0 = i0 * BINS;
    const int rp = min(i0 + 1, BINS - 1) * BINS;
    const int rf = min(max(f0, 0), BINS - 1) * BINS;
    const int cm = max(i1 - 1, 0);
    const int cc = i1;
    const int cp = min(i1 + 1, BINS - 1);
    const int cf = min(max(f1, 0), BINS - 1);

    // ALL sites masked: only fired lanes touch the LDS atomic engine (r10 form)
#define SITEQ(EA, EB, ADDR) do {                                               \
        const float w_ = fmaf(-0.5f, __fadd_rn(EA, EB), 0.01f);                \
        if (w_ > 0.0f)                                                         \
            atomicAdd(&lh[ADDR], (unsigned)fmaf(w_, QSCALE, 0.5f));            \
    } while (0)
    SITEQ(e0m, e1m, rm + cm); SITEQ(e0m, e10, rm + cc); SITEQ(e0m, e1p, rm + cp);
    SITEQ(e00, e1m, r0 + cm); SITEQ(e00, e10, r0 + cc); SITEQ(e00, e1p, r0 + cp);
    SITEQ(e0p, e1m, rp + cm); SITEQ(e0p, e10, rp + cc); SITEQ(e0p, e1p, rp + cp);
    SITEQ(e0f, e10, rf + cc);
    SITEQ(e00, e1f, r0 + cf);
#undef SITEQ
}

// ---- main path: dual 40KB sub-histograms -> summed coalesced u64-pair atomic
// flush into per-batch 640KB accumulator + exact u64 batch totals ----
__global__ __launch_bounds__(THREADS) void hist_part_kernel(
    const float* __restrict__ x, unsigned* __restrict__ accum,
    unsigned long long* __restrict__ totals)
{
    __shared__ __align__(16) unsigned lh[2 * NBINS2];   // 80KB: A=waves 0-7, B=waves 8-15
    uint4* lh4 = (uint4*)lh;
    for (int i = threadIdx.x; i < (2 * NBINS2) / 4; i += THREADS)
        lh4[i] = make_uint4(0u, 0u, 0u, 0u);
    __syncthreads();

    const int b  = blockIdx.x / PPB;
    const int pb = blockIdx.x % PPB;
    unsigned* __restrict__ myh = lh + ((threadIdx.x >> 9) ? NBINS2 : 0);
    const float4* __restrict__ xp = reinterpret_cast<const float4*>(
        x + (size_t)b * (NPOINTS * 2) + (size_t)pb * (CHUNK * 2));

    #pragma unroll
    for (int k = 0; k < (CHUNK / 2) / THREADS; ++k) {
        const float4 p = xp[threadIdx.x + k * THREADS];
        accum_point_q(myh, p.x, p.y);
        accum_point_q(myh, p.z, p.w);
    }
    __syncthreads();

    // flush: sum A+B bin-pairs, 5000 coalesced u64 atomics into the batch's accum row
    const uint2* __restrict__ lh2 = (const uint2*)lh;
    unsigned long long* __restrict__ acc2 =
        (unsigned long long*)(accum + (size_t)b * NBINS2);
    unsigned long long ts = 0ull;
    for (int i = threadIdx.x; i < NPAIR; i += THREADS) {
        const uint2 va = lh2[i];
        const uint2 vb = lh2[i + NPAIR];
        const unsigned s0 = va.x + vb.x;       // per-block per-bin < 2^31, no carry
        const unsigned s1 = va.y + vb.y;
        const unsigned long long pk =
            (unsigned long long)s0 | ((unsigned long long)s1 << 32);
        if (pk) atomicAdd(&acc2[i], pk);
        ts += (unsigned long long)s0 + s1;
    }
    #pragma unroll
    for (int off = 32; off > 0; off >>= 1) ts += __shfl_down(ts, off, 64);
    if ((threadIdx.x & 63) == 0) atomicAdd(&totals[b], ts);
}

// 160 blocks x 256 thr: (b = blk/10, chunk = blk%10); one uint4 (4 bins)/thread.
__global__ __launch_bounds__(256) void reduce_norm_kernel(
    const uint4* __restrict__ accum4, const unsigned long long* __restrict__ totals,
    float4* __restrict__ out4)
{
    const int b  = blockIdx.x / 10;
    const int ch = blockIdx.x % 10;
    const int t  = threadIdx.x;
    if (t < 250) {   // 250 uint4 = 1000 bins per chunk
        const int idx = b * (NBINS2 / 4) + ch * 250 + t;
        const uint4 v = accum4[idx];
        const double fac = QINV / ((double)totals[b] * QINV + 1e-5);
        out4[idx] = make_float4(
            (float)((double)v.x * fac), (float)((double)v.y * fac),
            (float)((double)v.z * fac), (float)((double)v.w * fac));
    }
}

// ---- fallback path (ws too small): float LDS hist + global atomic flush ----
__device__ __forceinline__ void accum_point_f(float* lh, float x0, float x1) {
    int i0 = __float2int_rd(__fmul_rn(x0, 100.0f)); i0 = min(max(i0, 0), BINS - 1);
    int i1 = __float2int_rd(__fmul_rn(x1, 100.0f)); i1 = min(max(i1, 0), BINS - 1);
    const float fi0 = (float)i0, fi1 = (float)i1;
    const float c00 = __fmul_rn(0.01f, fi0 + 0.5f);
    const float c10 = __fmul_rn(0.01f, fi1 + 0.5f);
    const float e00 = fabsf(__fsub_rn(x0, c00));
    const float e10 = fabsf(__fsub_rn(x1, c10));
    float e0m = fabsf(__fsub_rn(x0, __fmul_rn(0.01f, fi0 - 0.5f)));
    float e0p = fabsf(__fsub_rn(x0, __fmul_rn(0.01f, fi0 + 1.5f)));
    float e1m = fabsf(__fsub_rn(x1, __fmul_rn(0.01f, fi1 - 0.5f)));
    float e1p = fabsf(__fsub_rn(x1, __fmul_rn(0.01f, fi1 + 1.5f)));
    e0m = (i0 > 0)        ? e0m : 1e9f;
    e0p = (i0 < BINS - 1) ? e0p : 1e9f;
    e1m = (i1 > 0)        ? e1m : 1e9f;
    e1p = (i1 < BINS - 1) ? e1p : 1e9f;
    const bool up0 = (x0 > c00), up1 = (x1 > c10);
    const int   f0  = up0 ? i0 + 2 : i0 - 2;
    const int   f1  = up1 ? i1 + 2 : i1 - 2;
    const float ff0 = up0 ? fi0 + 2.0f : fi0 - 2.0f;
    const float ff1 = up1 ? fi1 + 2.0f : fi1 - 2.0f;
    float e0f = fabsf(__fsub_rn(x0, __fmul_rn(0.01f, ff0 + 0.5f)));
    float e1f = fabsf(__fsub_rn(x1, __fmul_rn(0.01f, ff1 + 0.5f)));
    e0f = ((unsigned)f0 < (unsigned)BINS) ? e0f : 1e9f;
    e1f = ((unsigned)f1 < (unsigned)BINS) ? e1f : 1e9f;
    const int rm = max(i0 - 1, 0) * BINS;
    const int r0 = i0 * BINS;
    const int rp = min(i0 + 1, BINS - 1) * BINS;
    const int rf = min(max(f0, 0), BINS - 1) * BINS;
    const int cm = max(i1 - 1, 0);
    const int cc = i1;
    const int cp = min(i1 + 1, BINS - 1);
    const int cf = min(max(f1, 0), BINS - 1);
#define SITEF(EA, EB, ADDR) do {                                               \
        const float w_ = fmaf(-0.5f, __fadd_rn(EA, EB), 0.01f);                \
        if (w_ > 0.0f) unsafeAtomicAdd(&lh[ADDR], w_);                         \
    } while (0)
    SITEF(e0m, e1m, rm + cm); SITEF(e0m, e10, rm + cc); SITEF(e0m, e1p, rm + cp);
    SITEF(e00, e1m, r0 + cm); SITEF(e00, e10, r0 + cc); SITEF(e00, e1p, r0 + cp);
    SITEF(e0p, e1m, rp + cm); SITEF(e0p, e10, rp + cc); SITEF(e0p, e1p, rp + cp);
    SITEF(e0f, e10, rf + cc);
    SITEF(e00, e1f, r0 + cf);
#undef SITEF
}

__global__ __launch_bounds__(THREADS) void hist_accum_kernel(
    const float* __restrict__ x, float* __restrict__ out)
{
    __shared__ __align__(16) float lh[NBINS2];
    float4* lh4 = (float4*)lh;
    for (int i = threadIdx.x; i < NBINS2 / 4; i += THREADS)
        lh4[i] = make_float4(0.f, 0.f, 0.f, 0.f);
    __syncthreads();
    const int b  = blockIdx.x / PPB;
    const int pb = blockIdx.x % PPB;
    const float4* __restrict__ xp = reinterpret_cast<const float4*>(
        x + (size_t)b * (NPOINTS * 2) + (size_t)pb * (CHUNK * 2));
    #pragma unroll
    for (int k = 0; k < (CHUNK / 2) / THREADS; ++k) {
        const float4 p = xp[threadIdx.x + k * THREADS];
        accum_point_f(lh, p.x, p.y);
        accum_point_f(lh, p.z, p.w);
    }
    __syncthreads();
    float* __restrict__ ob = out + (size_t)b * NBINS2;
    for (int i = threadIdx.x; i < NBINS2; i += THREADS) {
        const float v = lh[i];
        if (v != 0.0f) unsafeAtomicAdd(&ob[i], v);
    }
}

__global__ __launch_bounds__(1024) void norm_kernel(float* __restrict__ out)
{
    const int b = blockIdx.x;
    float* __restrict__ h = out + (size_t)b * NBINS2;
    float local = 0.0f;
    for (int i = threadIdx.x; i < NBINS2; i += 1024) local += h[i];
    #pragma unroll
    for (int off = 32; off > 0; off >>= 1) local += __shfl_down(local, off, 64);
    __shared__ float wsum[16];
    __shared__ float sden;
    if ((threadIdx.x & 63) == 0) wsum[threadIdx.x >> 6] = local;
    __syncthreads();
    if (threadIdx.x == 0) {
        float tt = 0.f;
        #pragma unroll
        for (int i = 0; i < 16; ++i) tt += wsum[i];
        sden = __fadd_rn(tt, 1e-5f);
    }
    __syncthreads();
    const float den = sden;
    for (int i = threadIdx.x; i < NBINS2; i += 1024) h[i] = __fdiv_rn(h[i], den);
}

extern "C" void kernel_launch(void* const* d_in, const int* in_sizes, int n_in,
                              void* d_out, int out_size, void* d_ws, size_t ws_size,
                              hipStream_t stream) {
    (void)in_sizes; (void)n_in;
    const float* x = (const float*)d_in[0];
    float* out = (float*)d_out;

    // ws layout: [0,128) totals u64[16]; [128, 128+640000) accum u32[16][10000]
    const size_t need = 128 + (size_t)NBATCH * NBINS2 * sizeof(unsigned);
    if (ws_size >= need) {
        unsigned long long* totals = (unsigned long long*)d_ws;
        unsigned* accum = (unsigned*)((char*)d_ws + 128);
        hipMemsetAsync(d_ws, 0, need, stream);
        hist_part_kernel<<<NPART, THREADS, 0, stream>>>(x, accum, totals);
        reduce_norm_kernel<<<NBATCH * 10, 256, 0, stream>>>(
            (const uint4*)accum, totals, (float4*)out);
    } else {
        hipMemsetAsync(out, 0, (size_t)out_size * sizeof(float), stream);
        hist_accum_kernel<<<NPART, THREADS, 0, stream>>>(x, out);
        norm_kernel<<<NBATCH, 1024, 0, stream>>>(out);
    }
}